// Round 4
// baseline (4382.973 us; speedup 1.0000x reference)
//
#include <hip/hip_runtime.h>
#include <hip/hip_bf16.h>
#include <math.h>

typedef __hip_bfloat16 bf16;

static constexpr int B_ = 4;
static constexpr int C_ = 64;
static constexpr int H_ = 256;
static constexpr int W_ = 256;
static constexpr int P_ = H_ * W_;    // 65536
static constexpr int NP_ = B_ * P_;   // 262144

__device__ __forceinline__ float cvt(float x) { return x; }
__device__ __forceinline__ float cvt(bf16 x) { return __bfloat162float(x); }
__device__ __forceinline__ float geluf(float x) { return 0.5f * x * (1.0f + erff(x * 0.70710678118654752f)); }
__device__ __forceinline__ float sigm(float x) { return 1.0f / (1.0f + __expf(-x)); }
__device__ __forceinline__ void stv(float* p, float v) { *p = v; }
__device__ __forceinline__ void stv(bf16* p, float v) { *p = __float2bfloat16(v); }

// dtype-adaptive input load: bf=true -> bf16, else fp32
__device__ __forceinline__ float ldin(const void* p, int i, bool bf) {
    return bf ? __bfloat162float(((const bf16*)p)[i]) : ((const float*)p)[i];
}

// ---------------- dtype detector ----------------
__global__ __launch_bounds__(256) void k_detect(const unsigned int* __restrict__ x, int* __restrict__ flag) {
    __shared__ int red[256];
    int cnt = 0;
    for (int i = threadIdx.x; i < 4096; i += 256) {
        unsigned int u = x[i];
        unsigned int e = (u >> 7) & 0xFFu;
        cnt += (e >= 100u && e <= 140u) ? 1 : 0;
    }
    red[threadIdx.x] = cnt;
    __syncthreads();
    for (int s = 128; s > 0; s >>= 1) {
        if (threadIdx.x < s) red[threadIdx.x] += red[threadIdx.x + s];
        __syncthreads();
    }
    if (threadIdx.x == 0) flag[0] = (red[0] > 2048) ? 1 : 0;
}

// ---------------- per-pixel channel LayerNorm -> bf16 ----------------
template <int MODE>  // 0: fp32 ws input, 1: adaptive external input
__global__ __launch_bounds__(256) void k_ln(const void* __restrict__ in,
                                            const void* __restrict__ w,
                                            const void* __restrict__ b,
                                            bf16* __restrict__ out, float eps,
                                            const int* __restrict__ dtf) {
    const bool bf = dtf[0] != 0;
    __shared__ float swt[C_], sbt[C_];
    if (threadIdx.x < C_) {
        swt[threadIdx.x] = ldin(w, threadIdx.x, bf);
        sbt[threadIdx.x] = ldin(b, threadIdx.x, bf);
    }
    __syncthreads();
    int g = blockIdx.x * 256 + threadIdx.x;
    int bb = g >> 16;
    int p = g & (P_ - 1);
    int base = bb * C_ * P_ + p;
    float v[C_];
    float mu = 0.f;
#pragma unroll
    for (int c = 0; c < C_; ++c) {
        v[c] = (MODE == 1) ? ldin(in, base + c * P_, bf) : ((const float*)in)[base + c * P_];
        mu += v[c];
    }
    mu *= (1.0f / C_);
    float var = 0.f;
#pragma unroll
    for (int c = 0; c < C_; ++c) { float d = v[c] - mu; var += d * d; }
    var *= (1.0f / C_);
    float inv = rsqrtf(var + eps);
#pragma unroll
    for (int c = 0; c < C_; ++c)
        out[base + c * P_] = __float2bfloat16((v[c] - mu) * inv * swt[c] + sbt[c]);
}

// ---------------- pointwise 1x1 conv ----------------
template <int CIN, int COUT, int ACT, typename InT, typename OutT>
__global__ __launch_bounds__(256) void k_pw(const InT* __restrict__ in,
                                            const void* __restrict__ w,
                                            const void* __restrict__ bias,
                                            OutT* __restrict__ out,
                                            const int* __restrict__ dtf) {
    const bool bf = dtf[0] != 0;
    __shared__ float sw[COUT * CIN];
    __shared__ float sb[COUT];
    for (int i = threadIdx.x; i < COUT * CIN; i += 256) sw[i] = ldin(w, i, bf);
    if (threadIdx.x < COUT) sb[threadIdx.x] = bias ? ldin(bias, threadIdx.x, bf) : 0.f;
    __syncthreads();
    int g = blockIdx.x * 256 + threadIdx.x;
    int bb = g >> 16;
    int p = g & (P_ - 1);
    int ibase = bb * CIN * P_ + p;
    float v[CIN];
#pragma unroll
    for (int c = 0; c < CIN; ++c) v[c] = cvt(in[ibase + c * P_]);
    int obase = bb * COUT * P_ + p;
    for (int o = 0; o < COUT; ++o) {
        float acc = sb[o];
        const float* wr = &sw[o * CIN];
#pragma unroll
        for (int c = 0; c < CIN; ++c) acc = fmaf(wr[c], v[c], acc);
        if (ACT == 1) acc = geluf(acc);
        stv(&out[obase + o * P_], acc);
    }
}

// ---------------- MBConv: dw3x3+gelu on the fly -> mean over H,W ----------------
__global__ __launch_bounds__(256) void k_dwmean(const bf16* __restrict__ h,
                                                const void* __restrict__ dww,
                                                const void* __restrict__ dwb,
                                                float* __restrict__ sraw,
                                                const int* __restrict__ dtf) {
    const bool bf = dtf[0] != 0;
    __shared__ float red[256];
    int bc = blockIdx.x;       // b*64+c
    int c = bc & 63;
    int base = bc * P_;
    float w9[9];
#pragma unroll
    for (int k = 0; k < 9; ++k) w9[k] = ldin(dww, c * 9 + k, bf);
    float bv = ldin(dwb, c, bf);
    float acc = 0.f;
    for (int p = threadIdx.x; p < P_; p += 256) {
        int hr = p >> 8, x = p & 255;
        float s = bv;
#pragma unroll
        for (int kh = 0; kh < 3; ++kh) {
            int hh = hr + kh - 1;
            if ((unsigned)hh >= (unsigned)H_) continue;
#pragma unroll
            for (int kw = 0; kw < 3; ++kw) {
                int ww = x + kw - 1;
                if ((unsigned)ww >= (unsigned)W_) continue;
                s = fmaf(w9[kh * 3 + kw], cvt(h[base + hh * W_ + ww]), s);
            }
        }
        acc += geluf(s);
    }
    red[threadIdx.x] = acc;
    __syncthreads();
    for (int s2 = 128; s2 > 0; s2 >>= 1) {
        if (threadIdx.x < s2) red[threadIdx.x] += red[threadIdx.x + s2];
        __syncthreads();
    }
    if (threadIdx.x == 0) sraw[bc] = red[0] * (1.0f / P_);
}

// ---------------- SE MLP ----------------
__global__ __launch_bounds__(256) void k_se(const float* __restrict__ sraw,
                                            const void* __restrict__ w1,
                                            const void* __restrict__ w2,
                                            float* __restrict__ sfin,
                                            const int* __restrict__ dtf) {
    const bool bf = dtf[0] != 0;
    __shared__ float hbuf[B_ * 16];
    int t = threadIdx.x;
    if (t < B_ * 16) {
        int bb = t >> 4, j = t & 15;
        float a = 0.f;
        for (int c = 0; c < 64; ++c) a = fmaf(sraw[bb * 64 + c], ldin(w1, j * 64 + c, bf), a);
        hbuf[t] = a * sigm(a);
    }
    __syncthreads();
    int bb = t >> 6, c = t & 63;
    float a = 0.f;
    for (int j = 0; j < 16; ++j) a = fmaf(hbuf[bb * 16 + j], ldin(w2, c * 16 + j, bf), a);
    sfin[t] = sigm(a);
}

// ---------------- MBConv tail: recompute dw+gelu, scale, 1x1 conv, += residual Y ----------------
__global__ __launch_bounds__(256) void k_mb2(const bf16* __restrict__ h,
                                             const void* __restrict__ dww,
                                             const void* __restrict__ dwb,
                                             const void* __restrict__ w2,
                                             const void* __restrict__ b2,
                                             const float* __restrict__ sfin,
                                             float* __restrict__ Y,
                                             const int* __restrict__ dtf) {
    const bool bf = dtf[0] != 0;
    __shared__ float sw[64 * 64];
    __shared__ float sdw[64 * 9];
    __shared__ float sb2[64], sdb[64];
    __shared__ float ssc[B_ * 64];
    for (int i = threadIdx.x; i < 4096; i += 256) sw[i] = ldin(w2, i, bf);
    for (int i = threadIdx.x; i < 576; i += 256) sdw[i] = ldin(dww, i, bf);
    if (threadIdx.x < 64) {
        sb2[threadIdx.x] = ldin(b2, threadIdx.x, bf);
        sdb[threadIdx.x] = ldin(dwb, threadIdx.x, bf);
    }
    if (threadIdx.x < B_ * 64) ssc[threadIdx.x] = sfin[threadIdx.x];
    __syncthreads();
    int g = blockIdx.x * 256 + threadIdx.x;
    int bb = g >> 16;
    int p = g & (P_ - 1);
    int hr = p >> 8, x = p & 255;
    float t[64];
    for (int c = 0; c < 64; ++c) {
        float s = sdb[c];
        int base = (bb * 64 + c) * P_;
#pragma unroll
        for (int kh = 0; kh < 3; ++kh) {
            int hh = hr + kh - 1;
            if ((unsigned)hh >= (unsigned)H_) continue;
#pragma unroll
            for (int kw = 0; kw < 3; ++kw) {
                int ww = x + kw - 1;
                if ((unsigned)ww >= (unsigned)W_) continue;
                s = fmaf(sdw[c * 9 + kh * 3 + kw], cvt(h[base + hh * W_ + ww]), s);
            }
        }
        t[c] = geluf(s) * ssc[bb * 64 + c];
    }
    for (int o = 0; o < 64; ++o) {
        float acc = sb2[o];
        const float* wr = &sw[o * 64];
#pragma unroll
        for (int c = 0; c < 64; ++c) acc = fmaf(wr[c], t[c], acc);
        Y[(bb * 64 + o) * P_ + p] += acc;
    }
}

// ---------------- window self-attention ----------------
__global__ __launch_bounds__(256) void k_winattn(const bf16* __restrict__ xf,
                                                 const void* __restrict__ q1w,
                                                 const void* __restrict__ q1b,
                                                 const void* __restrict__ qkvw,
                                                 const void* __restrict__ outw,
                                                 float* __restrict__ Y,
                                                 const int* __restrict__ dtf) {
    const bool bf = dtf[0] != 0;
    __shared__ float s_xf[64 * 65];
    __shared__ float s_xq[64 * 33];
    __shared__ float s_qkv[64 * 97];
    __shared__ float s_o[64 * 33];
    int wid = blockIdx.x;
    int bb = wid >> 10;
    int wy = (wid >> 5) & 31;
    int wx = wid & 31;
    int h0 = wy * 8, w0 = wx * 8;
    int t0 = threadIdx.x;
    for (int idx = t0; idx < 4096; idx += 256) {
        int c = idx >> 6, t = idx & 63;
        int p = (h0 + (t >> 3)) * W_ + w0 + (t & 7);
        s_xf[t * 65 + c] = cvt(xf[(bb * 64 + c) * P_ + p]);
    }
    __syncthreads();
    for (int idx = t0; idx < 2048; idx += 256) {
        int o = idx >> 6, t = idx & 63;
        float acc = ldin(q1b, o, bf);
        for (int c = 0; c < 64; ++c) acc = fmaf(ldin(q1w, o * 64 + c, bf), s_xf[t * 65 + c], acc);
        s_xq[t * 33 + o] = acc;
    }
    __syncthreads();
    for (int idx = t0; idx < 6144; idx += 256) {
        int o = idx >> 6, t = idx & 63;
        float acc = 0.f;
        for (int c = 0; c < 32; ++c) acc = fmaf(ldin(qkvw, o * 32 + c, bf), s_xq[t * 33 + c], acc);
        s_qkv[t * 97 + o] = acc;
    }
    __syncthreads();
    float* s_sc = s_xf;
    for (int hh = 0; hh < 4; ++hh) {
        for (int idx = t0; idx < 4096; idx += 256) {
            int j = idx >> 6, i = idx & 63;
            float acc = 0.f;
#pragma unroll
            for (int d = 0; d < 8; ++d)
                acc = fmaf(s_qkv[i * 97 + hh * 8 + d], s_qkv[j * 97 + 32 + hh * 8 + d], acc);
            s_sc[i * 65 + j] = acc * 0.25f;
        }
        __syncthreads();
        if (t0 < 64) {
            int i = t0;
            float m = -1e30f;
            for (int j = 0; j < 64; ++j) m = fmaxf(m, s_sc[i * 65 + j]);
            float sum = 0.f;
            for (int j = 0; j < 64; ++j) { float e = __expf(s_sc[i * 65 + j] - m); s_sc[i * 65 + j] = e; sum += e; }
            float r = 1.0f / sum;
            for (int j = 0; j < 64; ++j) s_sc[i * 65 + j] *= r;
        }
        __syncthreads();
        for (int idx = t0; idx < 512; idx += 256) {
            int d = idx >> 6, i = idx & 63;
            float acc = 0.f;
            for (int j = 0; j < 64; ++j) acc = fmaf(s_sc[i * 65 + j], s_qkv[j * 97 + 64 + hh * 8 + d], acc);
            s_o[i * 33 + hh * 8 + d] = acc;
        }
        __syncthreads();
    }
    for (int idx = t0; idx < 2048; idx += 256) {
        int o = idx >> 6, t = idx & 63;
        float acc = 0.f;
        for (int c = 0; c < 32; ++c) acc = fmaf(ldin(outw, o * 32 + c, bf), s_o[t * 33 + c], acc);
        int p = (h0 + (t >> 3)) * W_ + w0 + (t & 7);
        Y[(bb * 64 + o) * P_ + p] += acc;
    }
}

// ---------------- strided 3x3 conv (pad=1) ----------------
template <int CIN, int COUT, int OS, int STRIDE>
__global__ __launch_bounds__(256) void k_sconv(const bf16* __restrict__ in,
                                               const void* __restrict__ w,
                                               const void* __restrict__ bias,
                                               float* __restrict__ out,
                                               const int* __restrict__ dtf) {
    const bool bf = dtf[0] != 0;
    int g = blockIdx.x * 256 + threadIdx.x;
    int ow = g % OS;
    int oh = (g / OS) % OS;
    int oc = (g / (OS * OS)) % COUT;
    int bb = g / (OS * OS * COUT);
    float acc = ldin(bias, oc, bf);
    for (int ic = 0; ic < CIN; ++ic) {
        int ibase = (bb * CIN + ic) * P_;
        int wbase = (oc * CIN + ic) * 9;
#pragma unroll
        for (int kh = 0; kh < 3; ++kh) {
            int ih = oh * STRIDE + kh - 1;
            if ((unsigned)ih >= (unsigned)H_) continue;
#pragma unroll
            for (int kw = 0; kw < 3; ++kw) {
                int iw = ow * STRIDE + kw - 1;
                if ((unsigned)iw >= (unsigned)W_) continue;
                acc = fmaf(ldin(w, wbase + kh * 3 + kw, bf), cvt(in[ibase + ih * W_ + iw]), acc);
            }
        }
    }
    out[g] = acc;
}

// ---------------- sr-branch LN+gelu+kv ----------------
__global__ __launch_bounds__(64) void k_srkv(const float* __restrict__ x1,
                                             const void* __restrict__ lnw,
                                             const void* __restrict__ lnb,
                                             const void* __restrict__ kvw,
                                             const void* __restrict__ kvb,
                                             float* __restrict__ k1,
                                             float* __restrict__ v1,
                                             const int* __restrict__ dtf) {
    const bool bf = dtf[0] != 0;
    int tok = blockIdx.x;
    int bb = tok >> 8;
    int n = tok & 255;
    int c = threadIdx.x;
    __shared__ float sv[64];
    __shared__ float sg[64];
    float v = x1[(bb * 64 + c) * 256 + n];
    sv[c] = v;
    __syncthreads();
    float mu = 0.f;
    for (int i = 0; i < 64; ++i) mu += sv[i];
    mu *= (1.0f / 64.0f);
    float var = 0.f;
    for (int i = 0; i < 64; ++i) { float d = sv[i] - mu; var += d * d; }
    var *= (1.0f / 64.0f);
    float xn = (v - mu) * rsqrtf(var + 1e-5f) * ldin(lnw, c, bf) + ldin(lnb, c, bf);
    sg[c] = geluf(xn);
    __syncthreads();
    float acc = ldin(kvb, c, bf);
    for (int j = 0; j < 64; ++j) acc = fmaf(ldin(kvw, c * 64 + j, bf), sg[j], acc);
    int kk = c >> 5;
    int jh = (c >> 4) & 1;
    int d = c & 15;
    float* dst = kk ? v1 : k1;
    dst[((bb * 2 + jh) * 256 + n) * 16 + d] = acc;
}

// ---------------- low-res cross attention ----------------
__global__ __launch_bounds__(256) void k_xattn(const float* __restrict__ iqd,
                                               const float* __restrict__ k1,
                                               const float* __restrict__ v1,
                                               float* __restrict__ o1sp) {
    int bid = blockIdx.x;
    int iblk = bid & 3;
    int j = (bid >> 2) & 1;
    int bb = bid >> 3;
    __shared__ float sk[256 * 16];
    __shared__ float svv[256 * 16];
    int kbase = ((bb * 2 + j) * 256) * 16;
    for (int idx = threadIdx.x; idx < 4096; idx += 256) { sk[idx] = k1[kbase + idx]; svv[idx] = v1[kbase + idx]; }
    __syncthreads();
    int i = iblk * 256 + threadIdx.x;
    float q[16];
    int qbase = ((bb * 32 + (i >> 5)) * 32 + (i & 31)) * 32 + j * 16;
#pragma unroll
    for (int d = 0; d < 16; ++d) q[d] = iqd[qbase + d];
    float m = -1e30f, l = 0.f, o[16];
#pragma unroll
    for (int d = 0; d < 16; ++d) o[d] = 0.f;
    for (int n = 0; n < 256; ++n) {
        float s = 0.f;
#pragma unroll
        for (int d = 0; d < 16; ++d) s = fmaf(q[d], sk[n * 16 + d], s);
        s *= 0.25f;
        float mn = fmaxf(m, s);
        float corr = __expf(m - mn);
        float e = __expf(s - mn);
        l = l * corr + e;
#pragma unroll
        for (int d = 0; d < 16; ++d) o[d] = fmaf(o[d], corr, e * svv[n * 16 + d]);
        m = mn;
    }
    float r = 1.0f / l;
#pragma unroll
    for (int d = 0; d < 16; ++d)
        o1sp[((bb * 32 + j * 16 + d) * 32 + (i >> 5)) * 32 + (i & 31)] = o[d] * r;
}

// ---------------- cu conv (x8 upsample folded), += Y[32:64) ----------------
__global__ __launch_bounds__(256) void k_cuconv(const float* __restrict__ o1sp,
                                                const void* __restrict__ w,
                                                const void* __restrict__ bias,
                                                float* __restrict__ Y,
                                                const int* __restrict__ dtf) {
    const bool bf = dtf[0] != 0;
    __shared__ float sw[32 * 32 * 9];
    for (int i = threadIdx.x; i < 9216; i += 256) sw[i] = ldin(w, i, bf);
    __syncthreads();
    int g = blockIdx.x * 256 + threadIdx.x;
    int bb = g >> 16;
    int p = g & 65535;
    int h = p >> 8, x = p & 255;
    float acc[32];
#pragma unroll
    for (int oc = 0; oc < 32; ++oc) acc[oc] = ldin(bias, oc, bf);
    for (int ic = 0; ic < 32; ++ic) {
        int ibase = (bb * 32 + ic) * 1024;
        float v[9];
#pragma unroll
        for (int kh = 0; kh < 3; ++kh)
#pragma unroll
            for (int kw = 0; kw < 3; ++kw) {
                int hh = h + kh - 1, ww = x + kw - 1;
                v[kh * 3 + kw] = ((unsigned)hh < (unsigned)H_ && (unsigned)ww < (unsigned)W_)
                                     ? o1sp[ibase + (hh >> 3) * 32 + (ww >> 3)] : 0.f;
            }
        for (int oc = 0; oc < 32; ++oc) {
            const float* wr = &sw[(oc * 32 + ic) * 9];
            float a = acc[oc];
#pragma unroll
            for (int k = 0; k < 9; ++k) a = fmaf(wr[k], v[k], a);
            acc[oc] = a;
        }
    }
#pragma unroll
    for (int oc = 0; oc < 32; ++oc) Y[(bb * 64 + 32 + oc) * P_ + p] += acc[oc];
}

// ---------------- fused gated-conv FFN (1x1-in + dw3x3 + gate + 1x1-out), per 8x8 tile ----------------
__global__ __launch_bounds__(256) void k_gcff(const bf16* __restrict__ z,
                                              const void* __restrict__ inw,
                                              const void* __restrict__ dww,
                                              const void* __restrict__ outw,
                                              float* __restrict__ Y,
                                              const int* __restrict__ dtf) {
    const bool bf = dtf[0] != 0;
    __shared__ __align__(16) char arena[60160];
    bf16* zs    = (bf16*)arena;             // [64][102] (100 halo px, pad)
    bf16* mid   = (bf16*)(arena + 13056);   // [128][102]
    float* sdw  = (float*)(arena + 39168);  // 1152
    bf16* sinw  = (bf16*)(arena + 43776);   // 128*64 bf16 (dead after mid)
    float* sow  = (float*)(arena + 43776);  // 4096 f32 (loaded after mid)
    bf16* gated = (bf16*)arena;             // [64][66] overlays zs (dead after mid)
    int wid = blockIdx.x;
    int bb = wid >> 10;
    int wy = (wid >> 5) & 31;
    int wx = wid & 31;
    int h0 = wy * 8, w0 = wx * 8;
    int tid = threadIdx.x;
    for (int i = tid; i < 1152; i += 256) sdw[i] = ldin(dww, i, bf);
    for (int i = tid; i < 8192; i += 256) sinw[i] = __float2bfloat16(ldin(inw, i, bf));
    for (int i = tid; i < 6400; i += 256) {
        int c = i / 100, px = i % 100;
        int hh = h0 + px / 10 - 1, ww = w0 + px % 10 - 1;
        float v = ((unsigned)hh < (unsigned)H_ && (unsigned)ww < (unsigned)W_)
                      ? cvt(z[(bb * 64 + c) * P_ + hh * W_ + ww]) : 0.f;
        zs[c * 102 + px] = __float2bfloat16(v);
    }
    __syncthreads();
    for (int i = tid; i < 12800; i += 256) {
        int oc = i / 100, px = i % 100;
        float acc = 0.f;
#pragma unroll
        for (int c = 0; c < 64; ++c) acc = fmaf(cvt(sinw[oc * 64 + c]), cvt(zs[c * 102 + px]), acc);
        mid[oc * 102 + px] = __float2bfloat16(acc);
    }
    __syncthreads();
    for (int i = tid; i < 4096; i += 256) sow[i] = ldin(outw, i, bf);
    for (int i = tid; i < 4096; i += 256) {
        int c = i >> 6, t = i & 63;
        int rt = t >> 3, ct = t & 7;
        float a = 0.f, g2 = 0.f;
#pragma unroll
        for (int kh = 0; kh < 3; ++kh)
#pragma unroll
            for (int kw = 0; kw < 3; ++kw) {
                int px = (rt + kh) * 10 + ct + kw;
                a = fmaf(sdw[c * 9 + kh * 3 + kw], cvt(mid[c * 102 + px]), a);
                g2 = fmaf(sdw[(c + 64) * 9 + kh * 3 + kw], cvt(mid[(c + 64) * 102 + px]), g2);
            }
        gated[c * 66 + t] = __float2bfloat16(geluf(a) * g2);
    }
    __syncthreads();
    for (int i = tid; i < 4096; i += 256) {
        int o = i >> 6, t = i & 63;
        float acc = 0.f;
#pragma unroll
        for (int c = 0; c < 64; ++c) acc = fmaf(sow[o * 64 + c], cvt(gated[c * 66 + t]), acc);
        int p = (h0 + (t >> 3)) * W_ + w0 + (t & 7);
        Y[(bb * 64 + o) * P_ + p] += acc;
    }
}

// ---------------- fused windowed channel attention (1x1 qkv + dw3x3 in-block) ----------------
__global__ __launch_bounds__(256) void k_chattn(const bf16* __restrict__ z,
                                                const void* __restrict__ qkvw,
                                                const void* __restrict__ dww,
                                                const void* __restrict__ outw,
                                                const void* __restrict__ tempw,
                                                float* __restrict__ Y,
                                                const int* __restrict__ dtf) {
    const bool bf = dtf[0] != 0;
    __shared__ __align__(16) char arena[56064];
    bf16* zs    = (bf16*)arena;             // [64][102]
    bf16* qkvh  = (bf16*)(arena + 13056);   // [48][102] chunk
    bf16* sq    = (bf16*)(arena + 22848);   // [192][66]
    bf16* swq   = (bf16*)(arena + 48192);   // 48*64 chunk weights
    float* sdwc = (float*)(arena + 54336);  // 48*9 chunk dw weights
    float* s_att = (float*)arena;           // [64][17] overlays zs (dead)
    bf16* s_oc  = (bf16*)(arena + 4352);    // [64][66]
    float* s_ow = (float*)(arena + 13056);  // 4096 overlays qkvh (dead)
    int wid = blockIdx.x;
    int bb = wid >> 10;
    int hp = (wid >> 5) & 31;
    int wp = wid & 31;
    int h0 = hp * 8, w0 = wp * 8;
    int tid = threadIdx.x;
    for (int i = tid; i < 6400; i += 256) {
        int c = i / 100, px = i % 100;
        int hh = h0 + px / 10 - 1, ww = w0 + px % 10 - 1;
        float v = ((unsigned)hh < (unsigned)H_ && (unsigned)ww < (unsigned)W_)
                      ? cvt(z[(bb * 64 + c) * P_ + hh * W_ + ww]) : 0.f;
        zs[c * 102 + px] = __float2bfloat16(v);
    }
    __syncthreads();
    for (int chunk = 0; chunk < 4; ++chunk) {
        int ch0 = chunk * 48;
        for (int i = tid; i < 3072; i += 256) swq[i] = __float2bfloat16(ldin(qkvw, ch0 * 64 + i, bf));
        for (int i = tid; i < 432; i += 256) sdwc[i] = ldin(dww, ch0 * 9 + i, bf);
        __syncthreads();
        for (int i = tid; i < 4800; i += 256) {
            int oc = i / 100, px = i % 100;
            float acc = 0.f;
#pragma unroll
            for (int c = 0; c < 64; ++c) acc = fmaf(cvt(swq[oc * 64 + c]), cvt(zs[c * 102 + px]), acc);
            qkvh[oc * 102 + px] = __float2bfloat16(acc);
        }
        __syncthreads();
        for (int i = tid; i < 3072; i += 256) {
            int cl = i >> 6, t = i & 63;
            int rt = t >> 3, ct = t & 7;
            float a = 0.f;
#pragma unroll
            for (int kh = 0; kh < 3; ++kh)
#pragma unroll
                for (int kw = 0; kw < 3; ++kw)
                    a = fmaf(sdwc[cl * 9 + kh * 3 + kw], cvt(qkvh[cl * 102 + (rt + kh) * 10 + ct + kw]), a);
            sq[(ch0 + cl) * 66 + t] = __float2bfloat16(a);
        }
        __syncthreads();
    }
    // L2 normalize q,k rows
    if (tid < 128) {
        int r = tid;
        float ss = 0.f;
        for (int t = 0; t < 64; ++t) { float v = cvt(sq[r * 66 + t]); ss = fmaf(v, v, ss); }
        float inv = 1.0f / fmaxf(sqrtf(ss), 1e-12f);
        for (int t = 0; t < 64; ++t) sq[r * 66 + t] = __float2bfloat16(cvt(sq[r * 66 + t]) * inv);
    }
    __syncthreads();
    for (int i = tid; i < 1024; i += 256) {
        int hh = i >> 8, d = (i >> 4) & 15, f = i & 15;
        float acc = 0.f;
        for (int t = 0; t < 64; ++t)
            acc = fmaf(cvt(sq[(hh * 16 + d) * 66 + t]), cvt(sq[(64 + hh * 16 + f) * 66 + t]), acc);
        s_att[(hh * 16 + d) * 17 + f] = acc * ldin(tempw, hh, bf);
    }
    __syncthreads();
    if (tid < 64) {
        int row = tid;
        float m = -1e30f;
        for (int f = 0; f < 16; ++f) m = fmaxf(m, s_att[row * 17 + f]);
        float sum = 0.f;
        for (int f = 0; f < 16; ++f) { float e = __expf(s_att[row * 17 + f] - m); s_att[row * 17 + f] = e; sum += e; }
        float r = 1.0f / sum;
        for (int f = 0; f < 16; ++f) s_att[row * 17 + f] *= r;
    }
    __syncthreads();
    for (int i = tid; i < 4096; i += 256) {
        int row = i >> 6, t = i & 63;
        int hh = row >> 4, d = row & 15;
        float acc = 0.f;
#pragma unroll
        for (int f = 0; f < 16; ++f)
            acc = fmaf(s_att[(hh * 16 + d) * 17 + f], cvt(sq[(128 + hh * 16 + f) * 66 + t]), acc);
        s_oc[row * 66 + t] = __float2bfloat16(acc);
    }
    for (int i = tid; i < 4096; i += 256) s_ow[i] = ldin(outw, i, bf);
    __syncthreads();
    for (int i = tid; i < 4096; i += 256) {
        int o = i >> 6, t = i & 63;
        float acc = 0.f;
#pragma unroll
        for (int c = 0; c < 64; ++c) acc = fmaf(s_ow[o * 64 + c], cvt(s_oc[c * 66 + t]), acc);
        int p = (h0 + (t >> 3)) * W_ + w0 + (t & 7);
        Y[(bb * 64 + o) * P_ + p] += acc;
    }
}

// ---------------- final 1x1 over concat([x, y]) -> adaptive dtype out ----------------
__global__ __launch_bounds__(256) void k_final(const void* __restrict__ x,
                                               const float* __restrict__ Yb,
                                               const void* __restrict__ w,
                                               const void* __restrict__ bias,
                                               void* __restrict__ out,
                                               const int* __restrict__ dtf) {
    const bool bf = dtf[0] != 0;
    __shared__ float sw[64 * 128];
    __shared__ float sb[64];
    for (int i = threadIdx.x; i < 8192; i += 256) sw[i] = ldin(w, i, bf);
    if (threadIdx.x < 64) sb[threadIdx.x] = ldin(bias, threadIdx.x, bf);
    __syncthreads();
    int g = blockIdx.x * 256 + threadIdx.x;
    int bb = g >> 16;
    int p = g & 65535;
    float xv[64], yv[64];
    int base = bb * 64 * P_ + p;
#pragma unroll
    for (int c = 0; c < 64; ++c) xv[c] = ldin(x, base + c * P_, bf);
#pragma unroll
    for (int c = 0; c < 64; ++c) yv[c] = Yb[base + c * P_];
    for (int o = 0; o < 64; ++o) {
        float acc = sb[o];
        const float* wr = &sw[o * 128];
#pragma unroll
        for (int c = 0; c < 64; ++c) acc = fmaf(wr[c], xv[c], acc);
#pragma unroll
        for (int c = 0; c < 64; ++c) acc = fmaf(wr[64 + c], yv[c], acc);
        if (bf) ((bf16*)out)[base + o * P_] = __float2bfloat16(acc);
        else    ((float*)out)[base + o * P_] = acc;
    }
}

extern "C" void kernel_launch(void* const* d_in, const int* in_sizes, int n_in,
                              void* d_out, int out_size, void* d_ws, size_t ws_size,
                              hipStream_t stream) {
    const void* x        = d_in[0];
    const void* norm_w   = d_in[1];
    const void* norm_b   = d_in[2];
    const void* conv1_w  = d_in[3];
    const void* conv1_b  = d_in[4];
    const void* conv2_w  = d_in[5];
    const void* conv2_b  = d_in[6];
    const void* mb_w1    = d_in[7];
    const void* mb_b1    = d_in[8];
    const void* mb_dw_w  = d_in[9];
    const void* mb_dw_b  = d_in[10];
    const void* se_w1    = d_in[11];
    const void* se_w2    = d_in[12];
    const void* mb_w2    = d_in[13];
    const void* mb_b2    = d_in[14];
    const void* ln_att_w = d_in[15];
    const void* ln_att_b = d_in[16];
    const void* q1_w     = d_in[17];
    const void* q1_b     = d_in[18];
    const void* qkv_w    = d_in[19];
    const void* to_out_w = d_in[20];
    const void* sr_w     = d_in[21];
    const void* sr_b     = d_in[22];
    const void* ln_sr_w  = d_in[23];
    const void* ln_sr_b  = d_in[24];
    const void* kv1_w    = d_in[25];
    const void* kv1_b    = d_in[26];
    const void* q2_w     = d_in[27];
    const void* q2_b     = d_in[28];
    const void* cd_w     = d_in[29];
    const void* cd_b     = d_in[30];
    const void* cu_w     = d_in[31];
    const void* cu_b     = d_in[32];
    const void* cln1_w   = d_in[33];
    const void* cln1_b   = d_in[34];
    const void* ff1_in_w = d_in[35];
    const void* ff1_dw_w = d_in[36];
    const void* ff1_out_w= d_in[37];
    const void* cln2_w   = d_in[38];
    const void* cln2_b   = d_in[39];
    const void* ca_temp  = d_in[40];
    const void* ca_qkv_w = d_in[41];
    const void* ca_dw_w  = d_in[42];
    const void* ca_out_w = d_in[43];
    const void* cln3_w   = d_in[44];
    const void* cln3_b   = d_in[45];
    const void* ff2_in_w = d_in[46];
    const void* ff2_dw_w = d_in[47];
    const void* ff2_out_w= d_in[48];

    // Workspace layout — peak 114 MiB, smalls at offset 0.
    char* ws = (char*)d_ws;
    int*   dtf   = (int*)ws;                    // @0
    float* s_raw = (float*)(ws + 4096);         // @4K
    float* s_fin = (float*)(ws + 8192);         // @8K
    float* iqd   = (float*)(ws + 65536);        // @64K   (512K)
    float* x1    = (float*)(ws + 589824);       // @576K  (256K)
    float* k1b   = (float*)(ws + 851968);       // @832K  (128K)
    float* v1b   = (float*)(ws + 983040);       // @960K  (128K)
    float* o1sp  = (float*)(ws + 1114112);      // @1088K (512K)
    float* Y     = (float*)(ws + 2097152);      // @2M    (64M)
    bf16*  T1    = (bf16*)(ws + 69206016);      // @66M   (32M)
    bf16*  IQ    = (bf16*)(ws + 102760448);     // @98M   (16M) -> ends 114M

    dim3 blk(256);
    dim3 gPix(NP_ / 256);    // 1024
    dim3 gWin(B_ * 32 * 32); // 4096

    k_detect<<<dim3(1), blk, 0, stream>>>((const unsigned int*)x, dtf);
    // input norm + conv1
    k_ln<1><<<gPix, blk, 0, stream>>>(x, norm_w, norm_b, T1, 1e-6f, dtf);
    k_pw<64, 64, 0, bf16, float><<<gPix, blk, 0, stream>>>(T1, conv1_w, conv1_b, Y, dtf);
    // MBConv (T1 = hidden h)
    k_pw<64, 64, 1, float, bf16><<<gPix, blk, 0, stream>>>(Y, mb_w1, mb_b1, T1, dtf);
    k_dwmean<<<dim3(B_ * C_), blk, 0, stream>>>(T1, mb_dw_w, mb_dw_b, s_raw, dtf);
    k_se<<<dim3(1), blk, 0, stream>>>(s_raw, se_w1, se_w2, s_fin, dtf);
    k_mb2<<<gPix, blk, 0, stream>>>(T1, mb_dw_w, mb_dw_b, mb_w2, mb_b2, s_fin, Y, dtf);
    // hybrid attention
    k_ln<0><<<gPix, blk, 0, stream>>>(Y, ln_att_w, ln_att_b, T1, 1e-5f, dtf);
    k_winattn<<<gWin, blk, 0, stream>>>(T1, q1_w, q1_b, qkv_w, to_out_w, Y, dtf);
    // cross-attn branch
    k_pw<64, 32, 0, bf16, bf16><<<gPix, blk, 0, stream>>>(T1, q2_w, q2_b, IQ, dtf);
    k_sconv<32, 32, 32, 8><<<dim3(512), blk, 0, stream>>>(IQ, cd_w, cd_b, iqd, dtf);
    k_sconv<64, 64, 16, 16><<<dim3(256), blk, 0, stream>>>(T1, sr_w, sr_b, x1, dtf);
    k_srkv<<<dim3(B_ * 256), dim3(64), 0, stream>>>(x1, ln_sr_w, ln_sr_b, kv1_w, kv1_b, k1b, v1b, dtf);
    k_xattn<<<dim3(32), blk, 0, stream>>>(iqd, k1b, v1b, o1sp);
    k_cuconv<<<gPix, blk, 0, stream>>>(o1sp, cu_w, cu_b, Y, dtf);
    // gcff #1
    k_ln<0><<<gPix, blk, 0, stream>>>(Y, cln1_w, cln1_b, T1, 1e-6f, dtf);
    k_gcff<<<gWin, blk, 0, stream>>>(T1, ff1_in_w, ff1_dw_w, ff1_out_w, Y, dtf);
    // channel attention
    k_ln<0><<<gPix, blk, 0, stream>>>(Y, cln2_w, cln2_b, T1, 1e-6f, dtf);
    k_chattn<<<gWin, blk, 0, stream>>>(T1, ca_qkv_w, ca_dw_w, ca_out_w, ca_temp, Y, dtf);
    // gcff #2
    k_ln<0><<<gPix, blk, 0, stream>>>(Y, cln3_w, cln3_b, T1, 1e-6f, dtf);
    k_gcff<<<gWin, blk, 0, stream>>>(T1, ff2_in_w, ff2_dw_w, ff2_out_w, Y, dtf);
    // fuse with block input
    k_final<<<gPix, blk, 0, stream>>>(x, Y, conv2_w, conv2_b, d_out, dtf);

    (void)in_sizes; (void)n_in; (void)out_size; (void)ws_size;
}

// Round 5
// 3199.964 us; speedup vs baseline: 1.3697x; 1.3697x over previous
//
#include <hip/hip_runtime.h>
#include <hip/hip_bf16.h>
#include <math.h>

typedef __hip_bfloat16 bf16;

static constexpr int B_ = 4;
static constexpr int C_ = 64;
static constexpr int H_ = 256;
static constexpr int W_ = 256;
static constexpr int P_ = H_ * W_;    // 65536
static constexpr int NP_ = B_ * P_;   // 262144

__device__ __forceinline__ float cvt(float x) { return x; }
__device__ __forceinline__ float cvt(bf16 x) { return __bfloat162float(x); }
__device__ __forceinline__ float geluf(float x) { return 0.5f * x * (1.0f + erff(x * 0.70710678118654752f)); }
__device__ __forceinline__ float sigm(float x) { return 1.0f / (1.0f + __expf(-x)); }
__device__ __forceinline__ void stv(float* p, float v) { *p = v; }
__device__ __forceinline__ void stv(bf16* p, float v) { *p = __float2bfloat16(v); }

// dtype-adaptive input load: bf=true -> bf16, else fp32
__device__ __forceinline__ float ldin(const void* p, int i, bool bf) {
    return bf ? __bfloat162float(((const bf16*)p)[i]) : ((const float*)p)[i];
}

// unpack two bf16 packed in a u32 (little endian: a = low half)
__device__ __forceinline__ void bf2x(unsigned u, float& a, float& b) {
    a = __uint_as_float(u << 16);
    b = __uint_as_float(u & 0xffff0000u);
}

// ---------------- dtype detector ----------------
__global__ __launch_bounds__(256) void k_detect(const unsigned int* __restrict__ x, int* __restrict__ flag) {
    __shared__ int red[256];
    int cnt = 0;
    for (int i = threadIdx.x; i < 4096; i += 256) {
        unsigned int u = x[i];
        unsigned int e = (u >> 7) & 0xFFu;
        cnt += (e >= 100u && e <= 140u) ? 1 : 0;
    }
    red[threadIdx.x] = cnt;
    __syncthreads();
    for (int s = 128; s > 0; s >>= 1) {
        if (threadIdx.x < s) red[threadIdx.x] += red[threadIdx.x + s];
        __syncthreads();
    }
    if (threadIdx.x == 0) flag[0] = (red[0] > 2048) ? 1 : 0;
}

// ---------------- head: LN(x) -> conv1 -> Y ; gelu(mb1 @ Y) -> T1 ----------------
__global__ __launch_bounds__(256) void k_head(const void* __restrict__ x,
                                              const void* __restrict__ lnw, const void* __restrict__ lnb,
                                              const void* __restrict__ w1, const void* __restrict__ b1,
                                              const void* __restrict__ w2, const void* __restrict__ b2,
                                              float* __restrict__ Y, bf16* __restrict__ T1,
                                              const int* __restrict__ dtf) {
    const bool bf = dtf[0] != 0;
    __shared__ bf16 s1[4096], s2[4096];
    __shared__ float sb1[64], sb2[64], slw[64], slb[64];
    for (int i = threadIdx.x; i < 4096; i += 256) {
        s1[i] = __float2bfloat16(ldin(w1, i, bf));
        s2[i] = __float2bfloat16(ldin(w2, i, bf));
    }
    if (threadIdx.x < 64) {
        sb1[threadIdx.x] = ldin(b1, threadIdx.x, bf);
        sb2[threadIdx.x] = ldin(b2, threadIdx.x, bf);
        slw[threadIdx.x] = ldin(lnw, threadIdx.x, bf);
        slb[threadIdx.x] = ldin(lnb, threadIdx.x, bf);
    }
    __syncthreads();
    int g = blockIdx.x * 256 + threadIdx.x;
    int bb = g >> 16, p = g & (P_ - 1);
    int base = bb * 64 * P_ + p;
    float v[64];
    float mu = 0.f;
#pragma unroll
    for (int c = 0; c < 64; ++c) { v[c] = ldin(x, base + c * P_, bf); mu += v[c]; }
    mu *= (1.0f / 64.0f);
    float var = 0.f;
#pragma unroll
    for (int c = 0; c < 64; ++c) { float d = v[c] - mu; var += d * d; }
    float inv = rsqrtf(var * (1.0f / 64.0f) + 1e-6f);
#pragma unroll
    for (int c = 0; c < 64; ++c) v[c] = (v[c] - mu) * inv * slw[c] + slb[c];
    float y[64];
    const unsigned* u1 = (const unsigned*)s1;
    for (int o = 0; o < 64; ++o) {
        float a = sb1[o];
#pragma unroll
        for (int cc = 0; cc < 32; ++cc) {
            float wa, wb;
            bf2x(u1[o * 32 + cc], wa, wb);
            a = fmaf(wa, v[2 * cc], fmaf(wb, v[2 * cc + 1], a));
        }
        y[o] = a;
        Y[base + o * P_] = a;
    }
    const unsigned* u2 = (const unsigned*)s2;
    for (int o = 0; o < 64; ++o) {
        float a = sb2[o];
#pragma unroll
        for (int cc = 0; cc < 32; ++cc) {
            float wa, wb;
            bf2x(u2[o * 32 + cc], wa, wb);
            a = fmaf(wa, y[2 * cc], fmaf(wb, y[2 * cc + 1], a));
        }
        T1[base + o * P_] = __float2bfloat16(geluf(a));
    }
}

// ---------------- per-pixel channel LayerNorm -> bf16 (fp32 ws input) ----------------
__global__ __launch_bounds__(256) void k_ln(const float* __restrict__ in,
                                            const void* __restrict__ w,
                                            const void* __restrict__ b,
                                            bf16* __restrict__ out, float eps,
                                            const int* __restrict__ dtf) {
    const bool bf = dtf[0] != 0;
    __shared__ float swt[C_], sbt[C_];
    if (threadIdx.x < C_) {
        swt[threadIdx.x] = ldin(w, threadIdx.x, bf);
        sbt[threadIdx.x] = ldin(b, threadIdx.x, bf);
    }
    __syncthreads();
    int g = blockIdx.x * 256 + threadIdx.x;
    int bb = g >> 16;
    int p = g & (P_ - 1);
    int base = bb * C_ * P_ + p;
    float v[C_];
    float mu = 0.f;
#pragma unroll
    for (int c = 0; c < C_; ++c) { v[c] = in[base + c * P_]; mu += v[c]; }
    mu *= (1.0f / C_);
    float var = 0.f;
#pragma unroll
    for (int c = 0; c < C_; ++c) { float d = v[c] - mu; var += d * d; }
    var *= (1.0f / C_);
    float inv = rsqrtf(var + eps);
#pragma unroll
    for (int c = 0; c < C_; ++c)
        out[base + c * P_] = __float2bfloat16((v[c] - mu) * inv * swt[c] + sbt[c]);
}

// ---------------- fused per-pixel LN (eps 1e-6) + 1x1 projection -> bf16 ----------------
template <int COUT>
__global__ __launch_bounds__(256) void k_pwln(const float* __restrict__ Yin,
                                              const void* __restrict__ lnw, const void* __restrict__ lnb,
                                              const void* __restrict__ w,
                                              bf16* __restrict__ out,
                                              const int* __restrict__ dtf) {
    const bool bf = dtf[0] != 0;
    __shared__ bf16 swb[COUT * 64];
    __shared__ float slw[64], slb[64];
    for (int i = threadIdx.x; i < COUT * 64; i += 256) swb[i] = __float2bfloat16(ldin(w, i, bf));
    if (threadIdx.x < 64) {
        slw[threadIdx.x] = ldin(lnw, threadIdx.x, bf);
        slb[threadIdx.x] = ldin(lnb, threadIdx.x, bf);
    }
    __syncthreads();
    int g = blockIdx.x * 256 + threadIdx.x;
    int bb = g >> 16, p = g & (P_ - 1);
    int base = bb * 64 * P_ + p;
    float v[64];
    float mu = 0.f;
#pragma unroll
    for (int c = 0; c < 64; ++c) { v[c] = Yin[base + c * P_]; mu += v[c]; }
    mu *= (1.0f / 64.0f);
    float var = 0.f;
#pragma unroll
    for (int c = 0; c < 64; ++c) { float d = v[c] - mu; var += d * d; }
    float inv = rsqrtf(var * (1.0f / 64.0f) + 1e-6f);
#pragma unroll
    for (int c = 0; c < 64; ++c) v[c] = (v[c] - mu) * inv * slw[c] + slb[c];
    int obase = bb * COUT * P_ + p;
    const unsigned* uw = (const unsigned*)swb;
    for (int o = 0; o < COUT; ++o) {
        float a = 0.f;
#pragma unroll
        for (int cc = 0; cc < 32; ++cc) {
            float wa, wb;
            bf2x(uw[o * 32 + cc], wa, wb);
            a = fmaf(wa, v[2 * cc], fmaf(wb, v[2 * cc + 1], a));
        }
        out[obase + o * P_] = __float2bfloat16(a);
    }
}

// ---------------- MBConv: dw3x3+gelu on the fly -> mean over H,W ----------------
__global__ __launch_bounds__(256) void k_dwmean(const bf16* __restrict__ h,
                                                const void* __restrict__ dww,
                                                const void* __restrict__ dwb,
                                                float* __restrict__ sraw,
                                                const int* __restrict__ dtf) {
    const bool bf = dtf[0] != 0;
    __shared__ float red[256];
    int bc = blockIdx.x;
    int c = bc & 63;
    int base = bc * P_;
    float w9[9];
#pragma unroll
    for (int k = 0; k < 9; ++k) w9[k] = ldin(dww, c * 9 + k, bf);
    float bv = ldin(dwb, c, bf);
    float acc = 0.f;
    for (int p = threadIdx.x; p < P_; p += 256) {
        int hr = p >> 8, x = p & 255;
        float s = bv;
#pragma unroll
        for (int kh = 0; kh < 3; ++kh) {
            int hh = hr + kh - 1;
            if ((unsigned)hh >= (unsigned)H_) continue;
#pragma unroll
            for (int kw = 0; kw < 3; ++kw) {
                int ww = x + kw - 1;
                if ((unsigned)ww >= (unsigned)W_) continue;
                s = fmaf(w9[kh * 3 + kw], cvt(h[base + hh * W_ + ww]), s);
            }
        }
        acc += geluf(s);
    }
    red[threadIdx.x] = acc;
    __syncthreads();
    for (int s2 = 128; s2 > 0; s2 >>= 1) {
        if (threadIdx.x < s2) red[threadIdx.x] += red[threadIdx.x + s2];
        __syncthreads();
    }
    if (threadIdx.x == 0) sraw[bc] = red[0] * (1.0f / P_);
}

// ---------------- SE MLP ----------------
__global__ __launch_bounds__(256) void k_se(const float* __restrict__ sraw,
                                            const void* __restrict__ w1,
                                            const void* __restrict__ w2,
                                            float* __restrict__ sfin,
                                            const int* __restrict__ dtf) {
    const bool bf = dtf[0] != 0;
    __shared__ float hbuf[B_ * 16];
    int t = threadIdx.x;
    if (t < B_ * 16) {
        int bb = t >> 4, j = t & 15;
        float a = 0.f;
        for (int c = 0; c < 64; ++c) a = fmaf(sraw[bb * 64 + c], ldin(w1, j * 64 + c, bf), a);
        hbuf[t] = a * sigm(a);
    }
    __syncthreads();
    int bb = t >> 6, c = t & 63;
    float a = 0.f;
    for (int j = 0; j < 16; ++j) a = fmaf(hbuf[bb * 16 + j], ldin(w2, c * 16 + j, bf), a);
    sfin[t] = sigm(a);
}

// ---------------- MBConv tail per window: dw+gelu+scale -> 1x1 (tiled) -> += Y ----------------
__global__ __launch_bounds__(256) void k_mb2w(const bf16* __restrict__ h,
                                              const void* __restrict__ dww, const void* __restrict__ dwb,
                                              const void* __restrict__ w2, const void* __restrict__ b2,
                                              const float* __restrict__ sfin,
                                              float* __restrict__ Y,
                                              const int* __restrict__ dtf) {
    const bool bf = dtf[0] != 0;
    __shared__ __align__(16) bf16 hs[64 * 102];     // 13056 B
    __shared__ __align__(16) bf16 ts[64 * 66];      // 8448 B
    __shared__ __align__(16) bf16 sw2T[64 * 64];    // 8192 B  [c][o]
    __shared__ float sdw[576], sdb[64], sb2[64], ssc[64];
    int wid = blockIdx.x;
    int bb = wid >> 10;
    int h0 = ((wid >> 5) & 31) * 8, w0 = (wid & 31) * 8;
    int tid = threadIdx.x;
    for (int i = tid; i < 6400; i += 256) {
        int c = i / 100, px = i - c * 100;
        int pr = px / 10, pc = px - pr * 10;
        int hh = h0 + pr - 1, ww = w0 + pc - 1;
        bf16 v = ((unsigned)hh < (unsigned)H_ && (unsigned)ww < (unsigned)W_)
                     ? h[(bb * 64 + c) * P_ + hh * W_ + ww] : __float2bfloat16(0.f);
        hs[c * 102 + px] = v;
    }
    for (int i = tid; i < 576; i += 256) sdw[i] = ldin(dww, i, bf);
    for (int i = tid; i < 4096; i += 256) {
        int c = i >> 6, o = i & 63;
        sw2T[c * 64 + o] = __float2bfloat16(ldin(w2, o * 64 + c, bf));
    }
    if (tid < 64) {
        sdb[tid] = ldin(dwb, tid, bf);
        sb2[tid] = ldin(b2, tid, bf);
        ssc[tid] = sfin[bb * 64 + tid];
    }
    __syncthreads();
    for (int i = tid; i < 4096; i += 256) {
        int c = i >> 6, t = i & 63;
        int rt = t >> 3, ct = t & 7;
        float s = sdb[c];
#pragma unroll
        for (int kh = 0; kh < 3; ++kh)
#pragma unroll
            for (int kw = 0; kw < 3; ++kw)
                s = fmaf(sdw[c * 9 + kh * 3 + kw], cvt(hs[c * 102 + (rt + kh) * 10 + ct + kw]), s);
        ts[c * 66 + t] = __float2bfloat16(geluf(s) * ssc[c]);
    }
    __syncthreads();
    int og = tid >> 4, pg = tid & 15;
    int o0 = og * 4, p0 = pg * 4;
    float acc[4][4] = {};
    const unsigned* wt = (const unsigned*)sw2T;
    const unsigned* tt = (const unsigned*)ts;
    for (int c = 0; c < 64; ++c) {
        float w0v, w1v, w2v, w3v, t0, t1, t2, t3;
        bf2x(wt[c * 32 + (o0 >> 1)], w0v, w1v);
        bf2x(wt[c * 32 + (o0 >> 1) + 1], w2v, w3v);
        bf2x(tt[c * 33 + (p0 >> 1)], t0, t1);
        bf2x(tt[c * 33 + (p0 >> 1) + 1], t2, t3);
        acc[0][0] = fmaf(w0v, t0, acc[0][0]); acc[0][1] = fmaf(w0v, t1, acc[0][1]);
        acc[0][2] = fmaf(w0v, t2, acc[0][2]); acc[0][3] = fmaf(w0v, t3, acc[0][3]);
        acc[1][0] = fmaf(w1v, t0, acc[1][0]); acc[1][1] = fmaf(w1v, t1, acc[1][1]);
        acc[1][2] = fmaf(w1v, t2, acc[1][2]); acc[1][3] = fmaf(w1v, t3, acc[1][3]);
        acc[2][0] = fmaf(w2v, t0, acc[2][0]); acc[2][1] = fmaf(w2v, t1, acc[2][1]);
        acc[2][2] = fmaf(w2v, t2, acc[2][2]); acc[2][3] = fmaf(w2v, t3, acc[2][3]);
        acc[3][0] = fmaf(w3v, t0, acc[3][0]); acc[3][1] = fmaf(w3v, t1, acc[3][1]);
        acc[3][2] = fmaf(w3v, t2, acc[3][2]); acc[3][3] = fmaf(w3v, t3, acc[3][3]);
    }
#pragma unroll
    for (int i = 0; i < 4; ++i)
#pragma unroll
        for (int j = 0; j < 4; ++j) {
            int t = p0 + j;
            int p = (h0 + (t >> 3)) * W_ + w0 + (t & 7);
            Y[(bb * 64 + o0 + i) * P_ + p] += acc[i][j] + sb2[o0 + i];
        }
}

// ---------------- window self-attention ----------------
__global__ __launch_bounds__(256) void k_winattn(const bf16* __restrict__ xf,
                                                 const void* __restrict__ q1w,
                                                 const void* __restrict__ q1b,
                                                 const void* __restrict__ qkvw,
                                                 const void* __restrict__ outw,
                                                 float* __restrict__ Y,
                                                 const int* __restrict__ dtf) {
    const bool bf = dtf[0] != 0;
    __shared__ float s_xf[64 * 65];
    __shared__ float s_xq[64 * 33];
    __shared__ float s_qkv[64 * 97];
    __shared__ float s_o[64 * 33];
    int wid = blockIdx.x;
    int bb = wid >> 10;
    int wy = (wid >> 5) & 31;
    int wx = wid & 31;
    int h0 = wy * 8, w0 = wx * 8;
    int t0 = threadIdx.x;
    for (int idx = t0; idx < 4096; idx += 256) {
        int c = idx >> 6, t = idx & 63;
        int p = (h0 + (t >> 3)) * W_ + w0 + (t & 7);
        s_xf[t * 65 + c] = cvt(xf[(bb * 64 + c) * P_ + p]);
    }
    __syncthreads();
    for (int idx = t0; idx < 2048; idx += 256) {
        int o = idx >> 6, t = idx & 63;
        float acc = ldin(q1b, o, bf);
        for (int c = 0; c < 64; ++c) acc = fmaf(ldin(q1w, o * 64 + c, bf), s_xf[t * 65 + c], acc);
        s_xq[t * 33 + o] = acc;
    }
    __syncthreads();
    for (int idx = t0; idx < 6144; idx += 256) {
        int o = idx >> 6, t = idx & 63;
        float acc = 0.f;
        for (int c = 0; c < 32; ++c) acc = fmaf(ldin(qkvw, o * 32 + c, bf), s_xq[t * 33 + c], acc);
        s_qkv[t * 97 + o] = acc;
    }
    __syncthreads();
    float* s_sc = s_xf;
    for (int hh = 0; hh < 4; ++hh) {
        for (int idx = t0; idx < 4096; idx += 256) {
            int j = idx >> 6, i = idx & 63;
            float acc = 0.f;
#pragma unroll
            for (int d = 0; d < 8; ++d)
                acc = fmaf(s_qkv[i * 97 + hh * 8 + d], s_qkv[j * 97 + 32 + hh * 8 + d], acc);
            s_sc[i * 65 + j] = acc * 0.25f;
        }
        __syncthreads();
        if (t0 < 64) {
            int i = t0;
            float m = -1e30f;
            for (int j = 0; j < 64; ++j) m = fmaxf(m, s_sc[i * 65 + j]);
            float sum = 0.f;
            for (int j = 0; j < 64; ++j) { float e = __expf(s_sc[i * 65 + j] - m); s_sc[i * 65 + j] = e; sum += e; }
            float r = 1.0f / sum;
            for (int j = 0; j < 64; ++j) s_sc[i * 65 + j] *= r;
        }
        __syncthreads();
        for (int idx = t0; idx < 512; idx += 256) {
            int d = idx >> 6, i = idx & 63;
            float acc = 0.f;
            for (int j = 0; j < 64; ++j) acc = fmaf(s_sc[i * 65 + j], s_qkv[j * 97 + 64 + hh * 8 + d], acc);
            s_o[i * 33 + hh * 8 + d] = acc;
        }
        __syncthreads();
    }
    for (int idx = t0; idx < 2048; idx += 256) {
        int o = idx >> 6, t = idx & 63;
        float acc = 0.f;
        for (int c = 0; c < 32; ++c) acc = fmaf(ldin(outw, o * 32 + c, bf), s_o[t * 33 + c], acc);
        int p = (h0 + (t >> 3)) * W_ + w0 + (t & 7);
        Y[(bb * 64 + o) * P_ + p] += acc;
    }
}

// ---------------- pointwise 1x1 conv (bf16 in -> bf16 out) ----------------
template <int CIN, int COUT>
__global__ __launch_bounds__(256) void k_pw(const bf16* __restrict__ in,
                                            const void* __restrict__ w,
                                            const void* __restrict__ bias,
                                            bf16* __restrict__ out,
                                            const int* __restrict__ dtf) {
    const bool bf = dtf[0] != 0;
    __shared__ float sw[COUT * CIN];
    __shared__ float sb[COUT];
    for (int i = threadIdx.x; i < COUT * CIN; i += 256) sw[i] = ldin(w, i, bf);
    if (threadIdx.x < COUT) sb[threadIdx.x] = bias ? ldin(bias, threadIdx.x, bf) : 0.f;
    __syncthreads();
    int g = blockIdx.x * 256 + threadIdx.x;
    int bb = g >> 16;
    int p = g & (P_ - 1);
    int ibase = bb * CIN * P_ + p;
    float v[CIN];
#pragma unroll
    for (int c = 0; c < CIN; ++c) v[c] = cvt(in[ibase + c * P_]);
    int obase = bb * COUT * P_ + p;
    for (int o = 0; o < COUT; ++o) {
        float acc = sb[o];
        const float* wr = &sw[o * CIN];
#pragma unroll
        for (int c = 0; c < CIN; ++c) acc = fmaf(wr[c], v[c], acc);
        out[obase + o * P_] = __float2bfloat16(acc);
    }
}

// ---------------- strided 3x3 conv (pad=1) ----------------
template <int CIN, int COUT, int OS, int STRIDE>
__global__ __launch_bounds__(256) void k_sconv(const bf16* __restrict__ in,
                                               const void* __restrict__ w,
                                               const void* __restrict__ bias,
                                               float* __restrict__ out,
                                               const int* __restrict__ dtf) {
    const bool bf = dtf[0] != 0;
    int g = blockIdx.x * 256 + threadIdx.x;
    int ow = g % OS;
    int oh = (g / OS) % OS;
    int oc = (g / (OS * OS)) % COUT;
    int bb = g / (OS * OS * COUT);
    float acc = ldin(bias, oc, bf);
    for (int ic = 0; ic < CIN; ++ic) {
        int ibase = (bb * CIN + ic) * P_;
        int wbase = (oc * CIN + ic) * 9;
#pragma unroll
        for (int kh = 0; kh < 3; ++kh) {
            int ih = oh * STRIDE + kh - 1;
            if ((unsigned)ih >= (unsigned)H_) continue;
#pragma unroll
            for (int kw = 0; kw < 3; ++kw) {
                int iw = ow * STRIDE + kw - 1;
                if ((unsigned)iw >= (unsigned)W_) continue;
                acc = fmaf(ldin(w, wbase + kh * 3 + kw, bf), cvt(in[ibase + ih * W_ + iw]), acc);
            }
        }
    }
    out[g] = acc;
}

// ---------------- sr-branch LN+gelu+kv ----------------
__global__ __launch_bounds__(64) void k_srkv(const float* __restrict__ x1,
                                             const void* __restrict__ lnw,
                                             const void* __restrict__ lnb,
                                             const void* __restrict__ kvw,
                                             const void* __restrict__ kvb,
                                             float* __restrict__ k1,
                                             float* __restrict__ v1,
                                             const int* __restrict__ dtf) {
    const bool bf = dtf[0] != 0;
    int tok = blockIdx.x;
    int bb = tok >> 8;
    int n = tok & 255;
    int c = threadIdx.x;
    __shared__ float sv[64];
    __shared__ float sg[64];
    float v = x1[(bb * 64 + c) * 256 + n];
    sv[c] = v;
    __syncthreads();
    float mu = 0.f;
    for (int i = 0; i < 64; ++i) mu += sv[i];
    mu *= (1.0f / 64.0f);
    float var = 0.f;
    for (int i = 0; i < 64; ++i) { float d = sv[i] - mu; var += d * d; }
    var *= (1.0f / 64.0f);
    float xn = (v - mu) * rsqrtf(var + 1e-5f) * ldin(lnw, c, bf) + ldin(lnb, c, bf);
    sg[c] = geluf(xn);
    __syncthreads();
    float acc = ldin(kvb, c, bf);
    for (int j = 0; j < 64; ++j) acc = fmaf(ldin(kvw, c * 64 + j, bf), sg[j], acc);
    int kk = c >> 5;
    int jh = (c >> 4) & 1;
    int d = c & 15;
    float* dst = kk ? v1 : k1;
    dst[((bb * 2 + jh) * 256 + n) * 16 + d] = acc;
}

// ---------------- low-res cross attention ----------------
__global__ __launch_bounds__(256) void k_xattn(const float* __restrict__ iqd,
                                               const float* __restrict__ k1,
                                               const float* __restrict__ v1,
                                               float* __restrict__ o1sp) {
    int bid = blockIdx.x;
    int iblk = bid & 3;
    int j = (bid >> 2) & 1;
    int bb = bid >> 3;
    __shared__ float sk[256 * 16];
    __shared__ float svv[256 * 16];
    int kbase = ((bb * 2 + j) * 256) * 16;
    for (int idx = threadIdx.x; idx < 4096; idx += 256) { sk[idx] = k1[kbase + idx]; svv[idx] = v1[kbase + idx]; }
    __syncthreads();
    int i = iblk * 256 + threadIdx.x;
    float q[16];
    int qbase = ((bb * 32 + (i >> 5)) * 32 + (i & 31)) * 32 + j * 16;
#pragma unroll
    for (int d = 0; d < 16; ++d) q[d] = iqd[qbase + d];
    float m = -1e30f, l = 0.f, o[16];
#pragma unroll
    for (int d = 0; d < 16; ++d) o[d] = 0.f;
    for (int n = 0; n < 256; ++n) {
        float s = 0.f;
#pragma unroll
        for (int d = 0; d < 16; ++d) s = fmaf(q[d], sk[n * 16 + d], s);
        s *= 0.25f;
        float mn = fmaxf(m, s);
        float corr = __expf(m - mn);
        float e = __expf(s - mn);
        l = l * corr + e;
#pragma unroll
        for (int d = 0; d < 16; ++d) o[d] = fmaf(o[d], corr, e * svv[n * 16 + d]);
        m = mn;
    }
    float r = 1.0f / l;
#pragma unroll
    for (int d = 0; d < 16; ++d)
        o1sp[((bb * 32 + j * 16 + d) * 32 + (i >> 5)) * 32 + (i & 31)] = o[d] * r;
}

// ---------------- cu conv (x8 upsample folded), += Y[32:64) ----------------
__global__ __launch_bounds__(256) void k_cuconv(const float* __restrict__ o1sp,
                                                const void* __restrict__ w,
                                                const void* __restrict__ bias,
                                                float* __restrict__ Y,
                                                const int* __restrict__ dtf) {
    const bool bf = dtf[0] != 0;
    __shared__ float sw[32 * 32 * 9];
    for (int i = threadIdx.x; i < 9216; i += 256) sw[i] = ldin(w, i, bf);
    __syncthreads();
    int g = blockIdx.x * 256 + threadIdx.x;
    int bb = g >> 16;
    int p = g & 65535;
    int h = p >> 8, x = p & 255;
    float acc[32];
#pragma unroll
    for (int oc = 0; oc < 32; ++oc) acc[oc] = ldin(bias, oc, bf);
    for (int ic = 0; ic < 32; ++ic) {
        int ibase = (bb * 32 + ic) * 1024;
        float v[9];
#pragma unroll
        for (int kh = 0; kh < 3; ++kh)
#pragma unroll
            for (int kw = 0; kw < 3; ++kw) {
                int hh = h + kh - 1, ww = x + kw - 1;
                v[kh * 3 + kw] = ((unsigned)hh < (unsigned)H_ && (unsigned)ww < (unsigned)W_)
                                     ? o1sp[ibase + (hh >> 3) * 32 + (ww >> 3)] : 0.f;
            }
        for (int oc = 0; oc < 32; ++oc) {
            const float* wr = &sw[(oc * 32 + ic) * 9];
            float a = acc[oc];
#pragma unroll
            for (int k = 0; k < 9; ++k) a = fmaf(wr[k], v[k], a);
            acc[oc] = a;
        }
    }
#pragma unroll
    for (int oc = 0; oc < 32; ++oc) Y[(bb * 64 + 32 + oc) * P_ + p] += acc[oc];
}

// ---------------- gcff tail: stage mid halo, dw+gate, tiled out proj, += Y ----------------
__global__ __launch_bounds__(256) void k_gcff2(const bf16* __restrict__ mid_g,
                                               const void* __restrict__ dww,
                                               const void* __restrict__ outw,
                                               float* __restrict__ Y,
                                               const int* __restrict__ dtf) {
    const bool bf = dtf[0] != 0;
    __shared__ __align__(16) char arena[39168];
    bf16* mid = (bf16*)arena;               // [128][102] = 26112 B
    bf16* ts = (bf16*)(arena + 26112);      // [64][66]   = 8448 B
    float* sdw = (float*)(arena + 34560);   // 1152 f32   = 4608 B
    bf16* sowT = (bf16*)arena;              // [c][o] 8192 B, overlays mid (dead)
    int wid = blockIdx.x;
    int bb = wid >> 10;
    int h0 = ((wid >> 5) & 31) * 8, w0 = (wid & 31) * 8;
    int tid = threadIdx.x;
    for (int i = tid; i < 1152; i += 256) sdw[i] = ldin(dww, i, bf);
    for (int i = tid; i < 12800; i += 256) {
        int c = i / 100, px = i - c * 100;
        int pr = px / 10, pc = px - pr * 10;
        int hh = h0 + pr - 1, ww = w0 + pc - 1;
        bf16 v = ((unsigned)hh < (unsigned)H_ && (unsigned)ww < (unsigned)W_)
                     ? mid_g[(bb * 128 + c) * P_ + hh * W_ + ww] : __float2bfloat16(0.f);
        mid[c * 102 + px] = v;
    }
    __syncthreads();
    for (int i = tid; i < 4096; i += 256) {
        int c = i >> 6, t = i & 63;
        int rt = t >> 3, ct = t & 7;
        float a = 0.f, g2 = 0.f;
#pragma unroll
        for (int kh = 0; kh < 3; ++kh)
#pragma unroll
            for (int kw = 0; kw < 3; ++kw) {
                int px = (rt + kh) * 10 + ct + kw;
                a = fmaf(sdw[c * 9 + kh * 3 + kw], cvt(mid[c * 102 + px]), a);
                g2 = fmaf(sdw[(c + 64) * 9 + kh * 3 + kw], cvt(mid[(c + 64) * 102 + px]), g2);
            }
        ts[c * 66 + t] = __float2bfloat16(geluf(a) * g2);
    }
    __syncthreads();
    for (int i = tid; i < 4096; i += 256) {
        int c = i >> 6, o = i & 63;
        sowT[c * 64 + o] = __float2bfloat16(ldin(outw, o * 64 + c, bf));
    }
    __syncthreads();
    int og = tid >> 4, pg = tid & 15;
    int o0 = og * 4, p0 = pg * 4;
    float acc[4][4] = {};
    const unsigned* wt = (const unsigned*)sowT;
    const unsigned* tt = (const unsigned*)ts;
    for (int c = 0; c < 64; ++c) {
        float w0v, w1v, w2v, w3v, t0, t1, t2, t3;
        bf2x(wt[c * 32 + (o0 >> 1)], w0v, w1v);
        bf2x(wt[c * 32 + (o0 >> 1) + 1], w2v, w3v);
        bf2x(tt[c * 33 + (p0 >> 1)], t0, t1);
        bf2x(tt[c * 33 + (p0 >> 1) + 1], t2, t3);
        acc[0][0] = fmaf(w0v, t0, acc[0][0]); acc[0][1] = fmaf(w0v, t1, acc[0][1]);
        acc[0][2] = fmaf(w0v, t2, acc[0][2]); acc[0][3] = fmaf(w0v, t3, acc[0][3]);
        acc[1][0] = fmaf(w1v, t0, acc[1][0]); acc[1][1] = fmaf(w1v, t1, acc[1][1]);
        acc[1][2] = fmaf(w1v, t2, acc[1][2]); acc[1][3] = fmaf(w1v, t3, acc[1][3]);
        acc[2][0] = fmaf(w2v, t0, acc[2][0]); acc[2][1] = fmaf(w2v, t1, acc[2][1]);
        acc[2][2] = fmaf(w2v, t2, acc[2][2]); acc[2][3] = fmaf(w2v, t3, acc[2][3]);
        acc[3][0] = fmaf(w3v, t0, acc[3][0]); acc[3][1] = fmaf(w3v, t1, acc[3][1]);
        acc[3][2] = fmaf(w3v, t2, acc[3][2]); acc[3][3] = fmaf(w3v, t3, acc[3][3]);
    }
#pragma unroll
    for (int i = 0; i < 4; ++i)
#pragma unroll
        for (int j = 0; j < 4; ++j) {
            int t = p0 + j;
            int p = (h0 + (t >> 3)) * W_ + w0 + (t & 7);
            Y[(bb * 64 + o0 + i) * P_ + p] += acc[i][j];
        }
}

// ---------------- channel attention tail: stage qkv halo chunks, dw, attn, tiled out, += Y --------
__global__ __launch_bounds__(256) void k_chattn2(const bf16* __restrict__ qkv_g,
                                                 const void* __restrict__ dww,
                                                 const void* __restrict__ outw,
                                                 const void* __restrict__ tempw,
                                                 float* __restrict__ Y,
                                                 const int* __restrict__ dtf) {
    const bool bf = dtf[0] != 0;
    __shared__ __align__(16) char arena[48896];
    bf16* sq = (bf16*)arena;                 // [192][66] = 25344
    bf16* chunkb = (bf16*)(arena + 25344);   // [64][102] = 13056
    float* sdwc = (float*)(arena + 38400);   // 576 f32 = 2304
    bf16* s_owT = (bf16*)(arena + 40704);    // [c][o] = 8192
    float* s_att = (float*)(arena + 25344);  // [64][17] = 4352 (overlay chunkb)
    bf16* s_oc = (bf16*)(arena + 29696);     // [64][66] = 8448 (end 38144 < 38400)
    int wid = blockIdx.x;
    int bb = wid >> 10;
    int h0 = ((wid >> 5) & 31) * 8, w0 = (wid & 31) * 8;
    int tid = threadIdx.x;
    for (int chunk = 0; chunk < 3; ++chunk) {
        int ch0 = chunk * 64;
        for (int i = tid; i < 6400; i += 256) {
            int c = i / 100, px = i - c * 100;
            int pr = px / 10, pc = px - pr * 10;
            int hh = h0 + pr - 1, ww = w0 + pc - 1;
            bf16 v = ((unsigned)hh < (unsigned)H_ && (unsigned)ww < (unsigned)W_)
                         ? qkv_g[(bb * 192 + ch0 + c) * P_ + hh * W_ + ww] : __float2bfloat16(0.f);
            chunkb[c * 102 + px] = v;
        }
        for (int i = tid; i < 576; i += 256) sdwc[i] = ldin(dww, ch0 * 9 + i, bf);
        __syncthreads();
        for (int i = tid; i < 4096; i += 256) {
            int c = i >> 6, t = i & 63;
            int rt = t >> 3, ct = t & 7;
            float a = 0.f;
#pragma unroll
            for (int kh = 0; kh < 3; ++kh)
#pragma unroll
                for (int kw = 0; kw < 3; ++kw)
                    a = fmaf(sdwc[c * 9 + kh * 3 + kw], cvt(chunkb[c * 102 + (rt + kh) * 10 + ct + kw]), a);
            sq[(ch0 + c) * 66 + t] = __float2bfloat16(a);
        }
        __syncthreads();
    }
    if (tid < 128) {
        int r = tid;
        float ss = 0.f;
        for (int t = 0; t < 64; ++t) { float v = cvt(sq[r * 66 + t]); ss = fmaf(v, v, ss); }
        float inv = 1.0f / fmaxf(sqrtf(ss), 1e-12f);
        for (int t = 0; t < 64; ++t) sq[r * 66 + t] = __float2bfloat16(cvt(sq[r * 66 + t]) * inv);
    }
    __syncthreads();
    for (int i = tid; i < 1024; i += 256) {
        int hh = i >> 8, d = (i >> 4) & 15, f = i & 15;
        float acc = 0.f;
        for (int t = 0; t < 64; ++t)
            acc = fmaf(cvt(sq[(hh * 16 + d) * 66 + t]), cvt(sq[(64 + hh * 16 + f) * 66 + t]), acc);
        s_att[(hh * 16 + d) * 17 + f] = acc * ldin(tempw, hh, bf);
    }
    __syncthreads();
    if (tid < 64) {
        int row = tid;
        float m = -1e30f;
        for (int f = 0; f < 16; ++f) m = fmaxf(m, s_att[row * 17 + f]);
        float sum = 0.f;
        for (int f = 0; f < 16; ++f) { float e = __expf(s_att[row * 17 + f] - m); s_att[row * 17 + f] = e; sum += e; }
        float r = 1.0f / sum;
        for (int f = 0; f < 16; ++f) s_att[row * 17 + f] *= r;
    }
    __syncthreads();
    for (int i = tid; i < 4096; i += 256) {
        int row = i >> 6, t = i & 63;
        int hh = row >> 4, d = row & 15;
        float acc = 0.f;
#pragma unroll
        for (int f = 0; f < 16; ++f)
            acc = fmaf(s_att[(hh * 16 + d) * 17 + f], cvt(sq[(128 + hh * 16 + f) * 66 + t]), acc);
        s_oc[row * 66 + t] = __float2bfloat16(acc);
    }
    for (int i = tid; i < 4096; i += 256) {
        int c = i >> 6, o = i & 63;
        s_owT[c * 64 + o] = __float2bfloat16(ldin(outw, o * 64 + c, bf));
    }
    __syncthreads();
    int og = tid >> 4, pg = tid & 15;
    int o0 = og * 4, p0 = pg * 4;
    float acc[4][4] = {};
    const unsigned* wt = (const unsigned*)s_owT;
    const unsigned* tt = (const unsigned*)s_oc;
    for (int c = 0; c < 64; ++c) {
        float w0v, w1v, w2v, w3v, t0, t1, t2, t3;
        bf2x(wt[c * 32 + (o0 >> 1)], w0v, w1v);
        bf2x(wt[c * 32 + (o0 >> 1) + 1], w2v, w3v);
        bf2x(tt[c * 33 + (p0 >> 1)], t0, t1);
        bf2x(tt[c * 33 + (p0 >> 1) + 1], t2, t3);
        acc[0][0] = fmaf(w0v, t0, acc[0][0]); acc[0][1] = fmaf(w0v, t1, acc[0][1]);
        acc[0][2] = fmaf(w0v, t2, acc[0][2]); acc[0][3] = fmaf(w0v, t3, acc[0][3]);
        acc[1][0] = fmaf(w1v, t0, acc[1][0]); acc[1][1] = fmaf(w1v, t1, acc[1][1]);
        acc[1][2] = fmaf(w1v, t2, acc[1][2]); acc[1][3] = fmaf(w1v, t3, acc[1][3]);
        acc[2][0] = fmaf(w2v, t0, acc[2][0]); acc[2][1] = fmaf(w2v, t1, acc[2][1]);
        acc[2][2] = fmaf(w2v, t2, acc[2][2]); acc[2][3] = fmaf(w2v, t3, acc[2][3]);
        acc[3][0] = fmaf(w3v, t0, acc[3][0]); acc[3][1] = fmaf(w3v, t1, acc[3][1]);
        acc[3][2] = fmaf(w3v, t2, acc[3][2]); acc[3][3] = fmaf(w3v, t3, acc[3][3]);
    }
#pragma unroll
    for (int i = 0; i < 4; ++i)
#pragma unroll
        for (int j = 0; j < 4; ++j) {
            int t = p0 + j;
            int p = (h0 + (t >> 3)) * W_ + w0 + (t & 7);
            Y[(bb * 64 + o0 + i) * P_ + p] += acc[i][j];
        }
}

// ---------------- final 1x1 over concat([x, y]) -> adaptive dtype out ----------------
__global__ __launch_bounds__(256) void k_final(const void* __restrict__ x,
                                               const float* __restrict__ Yb,
                                               const void* __restrict__ w,
                                               const void* __restrict__ bias,
                                               void* __restrict__ out,
                                               const int* __restrict__ dtf) {
    const bool bf = dtf[0] != 0;
    __shared__ float sw[64 * 128];
    __shared__ float sb[64];
    for (int i = threadIdx.x; i < 8192; i += 256) sw[i] = ldin(w, i, bf);
    if (threadIdx.x < 64) sb[threadIdx.x] = ldin(bias, threadIdx.x, bf);
    __syncthreads();
    int g = blockIdx.x * 256 + threadIdx.x;
    int bb = g >> 16;
    int p = g & 65535;
    float xv[64], yv[64];
    int base = bb * 64 * P_ + p;
#pragma unroll
    for (int c = 0; c < 64; ++c) xv[c] = ldin(x, base + c * P_, bf);
#pragma unroll
    for (int c = 0; c < 64; ++c) yv[c] = Yb[base + c * P_];
    for (int o = 0; o < 64; ++o) {
        float acc = sb[o];
        const float* wr = &sw[o * 128];
#pragma unroll
        for (int c = 0; c < 64; ++c) acc = fmaf(wr[c], xv[c], acc);
#pragma unroll
        for (int c = 0; c < 64; ++c) acc = fmaf(wr[64 + c], yv[c], acc);
        if (bf) ((bf16*)out)[base + o * P_] = __float2bfloat16(acc);
        else    ((float*)out)[base + o * P_] = acc;
    }
}

extern "C" void kernel_launch(void* const* d_in, const int* in_sizes, int n_in,
                              void* d_out, int out_size, void* d_ws, size_t ws_size,
                              hipStream_t stream) {
    const void* x        = d_in[0];
    const void* norm_w   = d_in[1];
    const void* norm_b   = d_in[2];
    const void* conv1_w  = d_in[3];
    const void* conv1_b  = d_in[4];
    const void* conv2_w  = d_in[5];
    const void* conv2_b  = d_in[6];
    const void* mb_w1    = d_in[7];
    const void* mb_b1    = d_in[8];
    const void* mb_dw_w  = d_in[9];
    const void* mb_dw_b  = d_in[10];
    const void* se_w1    = d_in[11];
    const void* se_w2    = d_in[12];
    const void* mb_w2    = d_in[13];
    const void* mb_b2    = d_in[14];
    const void* ln_att_w = d_in[15];
    const void* ln_att_b = d_in[16];
    const void* q1_w     = d_in[17];
    const void* q1_b     = d_in[18];
    const void* qkv_w    = d_in[19];
    const void* to_out_w = d_in[20];
    const void* sr_w     = d_in[21];
    const void* sr_b     = d_in[22];
    const void* ln_sr_w  = d_in[23];
    const void* ln_sr_b  = d_in[24];
    const void* kv1_w    = d_in[25];
    const void* kv1_b    = d_in[26];
    const void* q2_w     = d_in[27];
    const void* q2_b     = d_in[28];
    const void* cd_w     = d_in[29];
    const void* cd_b     = d_in[30];
    const void* cu_w     = d_in[31];
    const void* cu_b     = d_in[32];
    const void* cln1_w   = d_in[33];
    const void* cln1_b   = d_in[34];
    const void* ff1_in_w = d_in[35];
    const void* ff1_dw_w = d_in[36];
    const void* ff1_out_w= d_in[37];
    const void* cln2_w   = d_in[38];
    const void* cln2_b   = d_in[39];
    const void* ca_temp  = d_in[40];
    const void* ca_qkv_w = d_in[41];
    const void* ca_dw_w  = d_in[42];
    const void* ca_out_w = d_in[43];
    const void* cln3_w   = d_in[44];
    const void* cln3_b   = d_in[45];
    const void* ff2_in_w = d_in[46];
    const void* ff2_dw_w = d_in[47];
    const void* ff2_out_w= d_in[48];

    // Workspace: smalls @0, Y @2M (64M), T1 @66M (32M), IQ @98M (16M), MID/QKV @114M (96M) -> 210M peak
    char* ws = (char*)d_ws;
    int*   dtf   = (int*)ws;
    float* s_raw = (float*)(ws + 4096);
    float* s_fin = (float*)(ws + 8192);
    float* iqd   = (float*)(ws + 65536);
    float* x1    = (float*)(ws + 589824);
    float* k1b   = (float*)(ws + 851968);
    float* v1b   = (float*)(ws + 983040);
    float* o1sp  = (float*)(ws + 1114112);
    float* Y     = (float*)(ws + 2097152);
    bf16*  T1    = (bf16*)(ws + 69206016);
    bf16*  IQ    = (bf16*)(ws + 102760448);
    bf16*  MIDQ  = (bf16*)(ws + 119537664);

    dim3 blk(256);
    dim3 gPix(NP_ / 256);    // 1024
    dim3 gWin(B_ * 32 * 32); // 4096

    k_detect<<<dim3(1), blk, 0, stream>>>((const unsigned int*)x, dtf);
    // LN + conv1 -> Y ; mb1+gelu -> T1
    k_head<<<gPix, blk, 0, stream>>>(x, norm_w, norm_b, conv1_w, conv1_b, mb_w1, mb_b1, Y, T1, dtf);
    // MBConv SE + tail
    k_dwmean<<<dim3(B_ * C_), blk, 0, stream>>>(T1, mb_dw_w, mb_dw_b, s_raw, dtf);
    k_se<<<dim3(1), blk, 0, stream>>>(s_raw, se_w1, se_w2, s_fin, dtf);
    k_mb2w<<<gWin, blk, 0, stream>>>(T1, mb_dw_w, mb_dw_b, mb_w2, mb_b2, s_fin, Y, dtf);
    // hybrid attention
    k_ln<<<gPix, blk, 0, stream>>>(Y, ln_att_w, ln_att_b, T1, 1e-5f, dtf);
    k_winattn<<<gWin, blk, 0, stream>>>(T1, q1_w, q1_b, qkv_w, to_out_w, Y, dtf);
    // cross-attn branch
    k_pw<64, 32><<<gPix, blk, 0, stream>>>(T1, q2_w, q2_b, IQ, dtf);
    k_sconv<32, 32, 32, 8><<<dim3(512), blk, 0, stream>>>(IQ, cd_w, cd_b, iqd, dtf);
    k_sconv<64, 64, 16, 16><<<dim3(256), blk, 0, stream>>>(T1, sr_w, sr_b, x1, dtf);
    k_srkv<<<dim3(B_ * 256), dim3(64), 0, stream>>>(x1, ln_sr_w, ln_sr_b, kv1_w, kv1_b, k1b, v1b, dtf);
    k_xattn<<<dim3(32), blk, 0, stream>>>(iqd, k1b, v1b, o1sp);
    k_cuconv<<<gPix, blk, 0, stream>>>(o1sp, cu_w, cu_b, Y, dtf);
    // gcff #1 (fused LN + in-proj, then window tail)
    k_pwln<128><<<gPix, blk, 0, stream>>>(Y, cln1_w, cln1_b, ff1_in_w, MIDQ, dtf);
    k_gcff2<<<gWin, blk, 0, stream>>>(MIDQ, ff1_dw_w, ff1_out_w, Y, dtf);
    // channel attention (fused LN + qkv-proj, then window tail)
    k_pwln<192><<<gPix, blk, 0, stream>>>(Y, cln2_w, cln2_b, ca_qkv_w, MIDQ, dtf);
    k_chattn2<<<gWin, blk, 0, stream>>>(MIDQ, ca_dw_w, ca_out_w, ca_temp, Y, dtf);
    // gcff #2
    k_pwln<128><<<gPix, blk, 0, stream>>>(Y, cln3_w, cln3_b, ff2_in_w, MIDQ, dtf);
    k_gcff2<<<gWin, blk, 0, stream>>>(MIDQ, ff2_dw_w, ff2_out_w, Y, dtf);
    // fuse with block input
    k_final<<<gPix, blk, 0, stream>>>(x, Y, conv2_w, conv2_b, d_out, dtf);

    (void)in_sizes; (void)n_in; (void)out_size; (void)ws_size;
}